// Round 1
// baseline (1441.685 us; speedup 1.0000x reference)
//
#include <hip/hip_runtime.h>
#include <math.h>

#define V 23
#define HH 256
#define BB 512
#define LL 1024
#define NOUT 46  // 2V

__global__ __launch_bounds__(256, 2)
void daf_kernel(const int* __restrict__ xtok,
                const float* __restrict__ W1,
                const float* __restrict__ b1,
                const float* __restrict__ W2,
                const float* __restrict__ b2,
                float* __restrict__ out)
{
    __shared__ float sW1[V * HH];      // 23*256 floats, row s at sW1[s*256]
    __shared__ float sV[HH];           // relu(h_pre)
    __shared__ float sP[NOUT][4];      // partials per (j, wave)
    __shared__ int   sTok[LL];
    __shared__ int   sInv[V];

    const int tid = threadIdx.x;
    const int w   = tid >> 6;   // wave id 0..3
    const int l   = tid & 63;   // lane id
    const int b   = blockIdx.x;

    // ---- one-time init ----
    for (int idx = tid; idx < V * HH; idx += 256) sW1[idx] = W1[idx];
    for (int idx = tid; idx < LL; idx += 256) sTok[idx] = xtok[(size_t)b * LL + idx];
    if (tid < V) {
        // multiplicative inverse mod 23 by brute force (inv(0) := 0)
        int inv = 0;
        for (int j = 1; j < V; ++j) { if ((tid * j) % V == 1) { inv = j; break; } }
        sInv[tid] = inv;
    }

    // h_pre accumulated in double: stays within 1 ulp of exact c@W1+b1,
    // minimizing drift vs the np fp32 reference over 1024 sequential adds.
    double h_pre = (double)b1[tid];

    float b2A = 0.f, b2B = 0.f;
    if (l < V) { b2A = b2[l]; b2B = b2[l + V]; }

    // W2 chunk in registers: thread (w, l<46) holds W2[64w + ii][l], ii = 0..63
    float w2reg[64];
    if (l < NOUT) {
        #pragma unroll
        for (int ii = 0; ii < 64; ++ii)
            w2reg[ii] = W2[(size_t)(64 * w + ii) * NOUT + l];
    } else {
        #pragma unroll
        for (int ii = 0; ii < 64; ++ii) w2reg[ii] = 0.f;
    }

    __syncthreads();

    float* outb = out + (size_t)b * LL * V;

    for (int t = 0; t < LL; ++t) {
        // 1. publish v = relu(h_pre)   (thread tid owns h_pre[tid])
        float v = (float)(h_pre > 0.0 ? h_pre : 0.0);
        sV[tid] = v;
        __syncthreads();

        // 2. matvec: wave w covers i in [64w, 64w+64); lane j=l<46 computes
        //    partial_j^w with v via LDS wave-broadcast (all lanes same addr)
        if (l < NOUT) {
            const float4* pv = (const float4*)(sV + 64 * w);
            float a0 = 0.f, a1 = 0.f, a2 = 0.f, a3 = 0.f;
            #pragma unroll
            for (int q = 0; q < 16; ++q) {
                float4 vv = pv[q];
                a0 = fmaf(vv.x, w2reg[4 * q + 0], a0);
                a1 = fmaf(vv.y, w2reg[4 * q + 1], a1);
                a2 = fmaf(vv.z, w2reg[4 * q + 2], a2);
                a3 = fmaf(vv.w, w2reg[4 * q + 3], a3);
            }
            sP[l][w] = (a0 + a1) + (a2 + a3);
        }
        __syncthreads();

        // 3. reduce + dual argmax, REPLICATED in every wave (identical fp op
        //    order -> bitwise-identical k in all waves; no 3rd barrier needed)
        float netA = -INFINITY, netB = -INFINITY;
        if (l < V) {
            float4 pA = *(const float4*)&sP[l][0];
            float4 pB = *(const float4*)&sP[l + V][0];
            netA = b2A + ((pA.x + pA.y) + (pA.z + pA.w));
            netB = b2B + ((pB.x + pB.y) + (pB.z + pB.w));
        }
        float vA = netA, vB = netB;
        int   iA = l,    iB = l;
        #pragma unroll
        for (int off = 16; off >= 1; off >>= 1) {
            float oA  = __shfl_xor(vA, off);
            int   oiA = __shfl_xor(iA, off);
            bool  tA  = (oA > vA) || (oA == vA && oiA < iA);  // first-max tie-break
            vA = tA ? oA : vA;  iA = tA ? oiA : iA;
            float oB  = __shfl_xor(vB, off);
            int   oiB = __shfl_xor(iB, off);
            bool  tB  = (oB > vB) || (oB == vB && oiB < iB);
            vB = tB ? oB : vB;  iB = tB ? oiB : iB;
        }
        int loc = __shfl(iA, 0);
        int sc  = __shfl(iB, 0);

        // 4. modular arithmetic: k = (inv(sc) * ((a0 - loc) mod 23)) mod 23
        int a0t = sTok[t];
        int m = a0t - loc;
        m += (m >> 31) & V;            // m in [0, 23)
        int inv = sInv[sc];
        int k = (m * inv) % V;         // compiler magic-multiply for %23

        // 5. h update: h_pre += W1[k][tid]  (stride-1 LDS, conflict-free)
        h_pre += (double)sW1[k * HH + tid];

        // 6. emit one-hot
        if (tid == 0) outb[t * V + k] = 1.0f;
    }
}

extern "C" void kernel_launch(void* const* d_in, const int* in_sizes, int n_in,
                              void* d_out, int out_size, void* d_ws, size_t ws_size,
                              hipStream_t stream) {
    const int*   xtok = (const int*)d_in[0];
    const float* W1   = (const float*)d_in[1];
    const float* b1   = (const float*)d_in[2];
    const float* W2   = (const float*)d_in[3];
    const float* b2   = (const float*)d_in[4];
    float* out = (float*)d_out;

    // d_out is poisoned 0xAA before every launch -> zero it, then scatter 1.0s
    hipMemsetAsync(out, 0, (size_t)out_size * sizeof(float), stream);
    daf_kernel<<<BB, 256, 0, stream>>>(xtok, W1, b1, W2, b2, out);
}

// Round 2
// 961.733 us; speedup vs baseline: 1.4990x; 1.4990x over previous
//
#include <hip/hip_runtime.h>
#include <math.h>

#define V 23
#define HH 256
#define BB 512
#define LL 1024
#define NOUT 46  // 2V

// Latency-chain kernel: one block per batch chain, 1024 strictly-serial steps.
// Design: ONE barrier per step (partials rendezvous only; sV is wave-local),
// no global memory ops inside the loop (k buffered in sK, written at end),
// dual argmax via a single u64-key butterfly over 32-lane halves with the
// modular inverse riding in the key payload.
__global__ __launch_bounds__(256, 2)
void daf_kernel(const int* __restrict__ xtok,
                const float* __restrict__ W1,
                const float* __restrict__ b1,
                const float* __restrict__ W2,
                const float* __restrict__ b2,
                float* __restrict__ out)
{
    __shared__ float sW1[V * HH];     // W1 rows for the h-update
    __shared__ float sV[HH];          // relu(h); wave w only touches [64w,64w+64)
    __shared__ float sP[2][56][4];    // partials [parity][lane][wave], dbl-buffered
    __shared__ int   sTok[LL];
    __shared__ int   sK[LL];          // emitted symbols; flushed to global at end

    const int tid = threadIdx.x;
    const int w   = tid >> 6;
    const int l   = tid & 63;
    const int b   = blockIdx.x;

    for (int i = tid; i < V * HH; i += 256) sW1[i] = W1[i];
    for (int i = tid; i < LL; i += 256) sTok[i] = xtok[(size_t)b * LL + i];

    // Lane roles: lanes 0..22 own net[:V] (loc), lanes 32..54 own net[V:] (scale).
    // Butterfly offsets <=16 never cross the 32-lane boundary, so one butterfly
    // reduces both halves independently.
    const bool activeA = (l < V);
    const bool activeB = (l >= 32 && l < 32 + V);
    const bool active  = activeA || activeB;
    const int  col     = activeA ? l : (activeB ? (l - 32 + V) : 0);
    const int  j       = activeA ? l : (activeB ? (l - 32) : 31);

    // h_pre in double: 1024 sequential adds stay within 1 ulp of exact c@W1+b1.
    double h_pre = (double)b1[tid];

    const float bias = active ? b2[col] : 0.f;

    // W2 chunk in registers: lane holds W2[64w+ii][col]
    float w2reg[64];
    #pragma unroll
    for (int ii = 0; ii < 64; ++ii)
        w2reg[ii] = active ? W2[(size_t)(64 * w + ii) * NOUT + col] : 0.f;

    // Key payload: byte1 = 31-j (ties -> smaller j wins, = np first-max),
    // byte0 = inv(j) mod V so the winner's inverse needs no LDS lookup.
    int invj = 0;
    if (active) { for (int q = 1; q < V; ++q) if ((j * q) % V == 1) { invj = q; break; } }
    const unsigned paybase = ((unsigned)(31 - j) << 8) | (unsigned)invj;

    __syncthreads();

    for (int t = 0; t < LL; ++t) {
        const int tok = sTok[t];

        // publish v = relu(h); consumed only by this wave's own matvec chunk
        float v = (float)(h_pre > 0.0 ? h_pre : 0.0);
        sV[tid] = v;

        // matvec partial: wave w covers i in [64w,64w+64); LDS broadcast reads
        const float4* pv = (const float4*)(sV + 64 * w);
        float a0 = 0.f, a1 = 0.f, a2 = 0.f, a3 = 0.f;
        #pragma unroll
        for (int q = 0; q < 16; ++q) {
            float4 vv = pv[q];
            a0 = fmaf(vv.x, w2reg[4 * q + 0], a0);
            a1 = fmaf(vv.y, w2reg[4 * q + 1], a1);
            a2 = fmaf(vv.z, w2reg[4 * q + 2], a2);
            a3 = fmaf(vv.w, w2reg[4 * q + 3], a3);
        }
        const int p = t & 1;
        if (active) sP[p][l][w] = (a0 + a1) + (a2 + a3);
        __syncthreads();   // the ONLY barrier per step (no VMEM in flight)

        // reduce 4 wave-partials + bias, pack sortable key, dual butterfly
        unsigned long long key = 0ULL;
        if (active) {
            float4 ps = *(const float4*)&sP[p][l][0];
            float net = bias + ((ps.x + ps.y) + (ps.z + ps.w));
            int ib = __float_as_int(net);
            unsigned mono = (ib < 0) ? ~(unsigned)ib : ((unsigned)ib ^ 0x80000000u);
            key = ((unsigned long long)mono << 24) | paybase;
        }
        #pragma unroll
        for (int off = 16; off >= 1; off >>= 1) {
            unsigned long long ok = __shfl_xor(key, off);
            if (ok > key) key = ok;
        }
        const unsigned payA = __shfl((unsigned)key, 0);   // loc winner (half A)
        const unsigned payB = __shfl((unsigned)key, 32);  // scale winner (half B)
        const int loc = 31 - (int)((payA >> 8) & 0xFF);
        const int inv = (int)(payB & 0xFF);

        int m = tok - loc;
        m += (m >> 31) & V;            // (tok - loc) mod 23
        const int k = (m * inv) % V;   // compiler magic-mul for %23

        h_pre += (double)sW1[k * HH + tid];   // stride-1, conflict-free
        if (tid == 0) sK[t] = k;
    }

    __syncthreads();
    float* outb = out + (size_t)b * LL * V;
    for (int t = tid; t < LL; t += 256)
        outb[t * V + sK[t]] = 1.0f;
}

extern "C" void kernel_launch(void* const* d_in, const int* in_sizes, int n_in,
                              void* d_out, int out_size, void* d_ws, size_t ws_size,
                              hipStream_t stream) {
    const int*   xtok = (const int*)d_in[0];
    const float* W1   = (const float*)d_in[1];
    const float* b1   = (const float*)d_in[2];
    const float* W2   = (const float*)d_in[3];
    const float* b2   = (const float*)d_in[4];
    float* out = (float*)d_out;

    // d_out poisoned 0xAA pre-launch: zero it, kernel scatters the 1.0s
    hipMemsetAsync(out, 0, (size_t)out_size * sizeof(float), stream);
    daf_kernel<<<BB, 256, 0, stream>>>(xtok, W1, b1, W2, b2, out);
}

// Round 4
// 780.419 us; speedup vs baseline: 1.8473x; 1.2323x over previous
//
#include <hip/hip_runtime.h>
#include <math.h>

#define V 23
#define HH 256
#define BB 512
#define LL 1024
#define NOUT 46  // 2V

// Multiplicative inverses mod 23, packed 5 bits/entry into two u64 scalars
// (entries 0..11 in T0, 12..22 in T1) so the inverse lookup is pure SALU.
constexpr unsigned long long packInv(int lo) {
    const int inv[23] = {0,1,12,8,6,14,4,10,3,18,7,21,2,16,5,20,13,19,9,17,15,11,22};
    unsigned long long t = 0;
    for (int i = 0; i < 12; ++i) {
        int idx = lo + i;
        if (idx < 23) t |= (unsigned long long)inv[idx] << (5 * i);
    }
    return t;
}
constexpr unsigned long long INV_T0 = packInv(0);
constexpr unsigned long long INV_T1 = packInv(12);

// VALU max-reduce step via DPP (no DS pipe, ~8 cy vs ~120 cy ds_swizzle)
#define DPPMAX(v, ctrl, rmask)                                                  \
    do {                                                                        \
        unsigned _t = (unsigned)__builtin_amdgcn_update_dpp(                    \
            (int)(v), (int)(v), (ctrl), (rmask), 0xF, false);                   \
        (v) = ((v) > _t) ? (v) : _t;                                            \
    } while (0)

__global__ __launch_bounds__(256, 2)
void daf_kernel(const int* __restrict__ xtok,
                const float* __restrict__ W1,
                const float* __restrict__ b1,
                const float* __restrict__ W2,
                const float* __restrict__ b2,
                float* __restrict__ out)
{
    __shared__ float sW1[V * HH];     // W1 rows for the h-update
    __shared__ float sV[HH];          // relu(h); wave w only touches [64w,64w+64)
    __shared__ float sP[2][64][4];    // partials [parity][lane][wave], dbl-buffered
    __shared__ int   sTok[LL];
    __shared__ int   sK[LL];          // emitted symbols; flushed to global at end

    const int tid = threadIdx.x;
    const int w   = tid >> 6;
    const int l   = tid & 63;
    const int b   = blockIdx.x;

    for (int i = tid; i < V * HH; i += 256) sW1[i] = W1[i];
    for (int i = tid; i < LL; i += 256) sTok[i] = xtok[(size_t)b * LL + i];

    // Lane roles: lanes 0..22 own net[:V] (loc), lanes 32..54 own net[V:] (scale).
    const bool activeA = (l < V);
    const bool activeB = (l >= 32 && l < 32 + V);
    const bool active  = activeA || activeB;
    const int  col     = activeA ? l : (activeB ? (l - 32 + V) : 0);

    // h_pre in double: 1024 sequential adds stay within 1 ulp of exact c@W1+b1.
    double h_pre = (double)b1[tid];

    const float bias = active ? b2[col] : 0.f;

    // W2 chunk in registers: lane holds W2[64w+ii][col]
    float w2reg[64];
    #pragma unroll
    for (int ii = 0; ii < 64; ++ii)
        w2reg[ii] = active ? W2[(size_t)(64 * w + ii) * NOUT + col] : 0.f;

    __syncthreads();

    for (int t = 0; t < LL; ++t) {
        const int tok = sTok[t];   // issued early; latency hidden under matvec

        // publish v = relu(h); consumed only by this wave's own matvec chunk
        float v = fmaxf((float)h_pre, 0.f);
        sV[tid] = v;

        // matvec partial: wave w covers i in [64w,64w+64); LDS broadcast reads
        const float4* pv = (const float4*)(sV + 64 * w);
        float a0 = 0.f, a1 = 0.f, a2 = 0.f, a3 = 0.f;
        #pragma unroll
        for (int q = 0; q < 16; ++q) {
            float4 vv = pv[q];
            a0 = fmaf(vv.x, w2reg[4 * q + 0], a0);
            a1 = fmaf(vv.y, w2reg[4 * q + 1], a1);
            a2 = fmaf(vv.z, w2reg[4 * q + 2], a2);
            a3 = fmaf(vv.w, w2reg[4 * q + 3], a3);
        }
        const int p = t & 1;
        sP[p][l][w] = (a0 + a1) + (a2 + a3);   // unconditional; junk lanes discarded
        __syncthreads();   // the ONLY barrier per step

        // reduce 4 wave-partials + bias -> monotone u32 (junk lanes -> 0)
        float4 ps = *(const float4*)&sP[p][l][0];
        float net = bias + ((ps.x + ps.y) + (ps.z + ps.w));
        int ib = __float_as_int(net);
        unsigned monoraw = (ib < 0) ? ~(unsigned)ib : ((unsigned)ib ^ 0x80000000u);
        const unsigned orig = active ? monoraw : 0u;  // lane's OWN key, preserved

        // dual 32-lane-half max-reduce on a separate register (VALU DPP only)
        unsigned red = orig;
        DPPMAX(red, 0xB1,  0xF);  // quad_perm xor1
        DPPMAX(red, 0x4E,  0xF);  // quad_perm xor2
        DPPMAX(red, 0x141, 0xF);  // row_half_mirror (combine 4-groups)
        DPPMAX(red, 0x140, 0xF);  // row_mirror      (combine 8-groups)
        DPPMAX(red, 0x142, 0xA);  // row_bcast15 into rows 1,3 (combine rows)
        const unsigned sA = (unsigned)__builtin_amdgcn_readlane((int)red, 16);
        const unsigned sB = (unsigned)__builtin_amdgcn_readlane((int)red, 48);

        // winner = lowest lane whose ORIGINAL key equals its half's max
        // (lowest lane == lowest index == np first-max tie-break)
        const unsigned cmpv = (l < 32) ? sA : sB;
        const unsigned long long bal = __ballot(orig == cmpv);
        const int loc = __builtin_ctzll(bal & 0xFFFFFFFFull);  // lane == col
        const int sc  = __builtin_ctzll(bal >> 32);

        // inverse mod 23 from packed scalar table (no LDS on the chain)
        const unsigned long long tt = (sc < 12) ? INV_T0 : INV_T1;
        const int sh  = 5 * (sc - ((sc >= 12) ? 12 : 0));
        const int inv = (int)((tt >> sh) & 31);

        int m = tok - loc;
        m += (m >> 31) & V;            // (tok - loc) mod 23
        const int k = (m * inv) % V;   // compiler magic-mul for %23

        h_pre += (double)sW1[k * HH + tid];   // stride-1, conflict-free
        if (tid == 0) sK[t] = k;
    }

    __syncthreads();
    float* outb = out + (size_t)b * LL * V;
    for (int t = tid; t < LL; t += 256)
        outb[t * V + sK[t]] = 1.0f;
}

extern "C" void kernel_launch(void* const* d_in, const int* in_sizes, int n_in,
                              void* d_out, int out_size, void* d_ws, size_t ws_size,
                              hipStream_t stream) {
    const int*   xtok = (const int*)d_in[0];
    const float* W1   = (const float*)d_in[1];
    const float* b1   = (const float*)d_in[2];
    const float* W2   = (const float*)d_in[3];
    const float* b2   = (const float*)d_in[4];
    float* out = (float*)d_out;

    // d_out poisoned 0xAA pre-launch: zero it, kernel scatters the 1.0s
    hipMemsetAsync(out, 0, (size_t)out_size * sizeof(float), stream);
    daf_kernel<<<BB, 256, 0, stream>>>(xtok, W1, b1, W2, b2, out);
}

// Round 6
// 779.340 us; speedup vs baseline: 1.8499x; 1.0014x over previous
//
#include <hip/hip_runtime.h>
#include <math.h>

#define V 23
#define HH 256
#define BB 512
#define LL 1024
#define NOUT 46  // 2V

// Multiplicative inverses mod 23, packed 5 bits/entry into two u64 scalars
// (entries 0..11 in T0, 12..22 in T1) so the inverse lookup is pure SALU.
constexpr unsigned long long packInv(int lo) {
    const int inv[23] = {0,1,12,8,6,14,4,10,3,18,7,21,2,16,5,20,13,19,9,17,15,11,22};
    unsigned long long t = 0;
    for (int i = 0; i < 12; ++i) {
        int idx = lo + i;
        if (idx < 23) t |= (unsigned long long)inv[idx] << (5 * i);
    }
    return t;
}
constexpr unsigned long long INV_T0 = packInv(0);
constexpr unsigned long long INV_T1 = packInv(12);

// VALU max-reduce step via DPP (no DS pipe, ~8 cy vs ~120 cy ds_swizzle)
#define DPPMAX(v, ctrl, rmask)                                                  \
    do {                                                                        \
        unsigned _t = (unsigned)__builtin_amdgcn_update_dpp(                    \
            (int)(v), (int)(v), (ctrl), (rmask), 0xF, false);                   \
        (v) = ((v) > _t) ? (v) : _t;                                            \
    } while (0)

__global__ __launch_bounds__(256, 2)
void daf_kernel(const int* __restrict__ xtok,
                const float* __restrict__ W1,
                const float* __restrict__ b1,
                const float* __restrict__ W2,
                const float* __restrict__ b2,
                float* __restrict__ out)
{
    __shared__ float sW1[V * HH];     // W1 rows for the h-update
    __shared__ float sV[HH];          // relu(h); wave w only touches [64w,64w+64)
    __shared__ float sP[2][64][4];    // partials [parity][lane][wave], dbl-buffered
    __shared__ int   sTok[LL];
    __shared__ int   sK[LL];          // emitted symbols; flushed to global at end

    const int tid = threadIdx.x;
    const int w   = tid >> 6;
    const int l   = tid & 63;
    const int b   = blockIdx.x;

    for (int i = tid; i < V * HH; i += 256) sW1[i] = W1[i];
    for (int i = tid; i < LL; i += 256) sTok[i] = xtok[(size_t)b * LL + i];

    // Lane roles: lanes 0..22 own net[:V] (loc), lanes 32..54 own net[V:] (scale).
    const bool activeA = (l < V);
    const bool activeB = (l >= 32 && l < 32 + V);
    const bool active  = activeA || activeB;
    const int  col     = activeA ? l : (activeB ? (l - 32 + V) : 0);

    // h_pre in double: 1024 sequential adds stay within 1 ulp of exact c@W1+b1.
    double h_pre = (double)b1[tid];

    const float bias = active ? b2[col] : 0.f;

    // W2 chunk: lane holds W2[64w+ii][col], ii=0..63, PINNED in VGPRs.
    // Without the asm barrier the compiler rematerializes these global loads
    // inside the t-loop (R4: VGPR_Count=56 => 64 VMEM loads/lane/step on the
    // critical chain). Per-scalar "+v" makes each value opaque; 128-bit "+v"
    // (float4) is unsupported ("tied indirect register inputs").
    float wreg[64];
    #pragma unroll
    for (int ii = 0; ii < 64; ++ii)
        wreg[ii] = active ? W2[(size_t)(64 * w + ii) * NOUT + col] : 0.f;
    #pragma unroll
    for (int ii = 0; ii < 64; ++ii) asm volatile("" : "+v"(wreg[ii]));

    __syncthreads();

    for (int t = 0; t < LL; ++t) {
        const int tok = sTok[t];   // issued early; latency hidden under matvec

        // publish v = relu(h); consumed only by this wave's own matvec chunk
        float v = fmaxf((float)h_pre, 0.f);
        sV[tid] = v;

        // matvec partial: wave w covers i in [64w,64w+64); LDS broadcast reads
        const float4* pv = (const float4*)(sV + 64 * w);
        float a0 = 0.f, a1 = 0.f, a2 = 0.f, a3 = 0.f;
        #pragma unroll
        for (int q = 0; q < 16; ++q) {
            float4 vv = pv[q];
            a0 = fmaf(vv.x, wreg[4 * q + 0], a0);
            a1 = fmaf(vv.y, wreg[4 * q + 1], a1);
            a2 = fmaf(vv.z, wreg[4 * q + 2], a2);
            a3 = fmaf(vv.w, wreg[4 * q + 3], a3);
        }
        const int p = t & 1;
        sP[p][l][w] = (a0 + a1) + (a2 + a3);   // unconditional; junk lanes discarded
        __syncthreads();   // the ONLY barrier per step

        // reduce 4 wave-partials + bias -> monotone u32 (junk lanes -> 0)
        float4 ps = *(const float4*)&sP[p][l][0];
        float net = bias + ((ps.x + ps.y) + (ps.z + ps.w));
        int ib = __float_as_int(net);
        unsigned monoraw = (ib < 0) ? ~(unsigned)ib : ((unsigned)ib ^ 0x80000000u);
        const unsigned orig = active ? monoraw : 0u;  // lane's OWN key, preserved

        // dual 32-lane-half max-reduce on a separate register (VALU DPP only)
        unsigned red = orig;
        DPPMAX(red, 0xB1,  0xF);  // quad_perm xor1
        DPPMAX(red, 0x4E,  0xF);  // quad_perm xor2
        DPPMAX(red, 0x141, 0xF);  // row_half_mirror (combine 4-groups)
        DPPMAX(red, 0x140, 0xF);  // row_mirror      (combine 8-groups)
        DPPMAX(red, 0x142, 0xA);  // row_bcast15 into rows 1,3 (combine rows)
        const unsigned sA = (unsigned)__builtin_amdgcn_readlane((int)red, 16);
        const unsigned sB = (unsigned)__builtin_amdgcn_readlane((int)red, 48);

        // winner = lowest lane whose ORIGINAL key equals its half's max
        // (lowest lane == lowest index == np first-max tie-break)
        const unsigned cmpv = (l < 32) ? sA : sB;
        const unsigned long long bal = __ballot(orig == cmpv);
        const int loc = __builtin_ctzll(bal & 0xFFFFFFFFull);  // lane == col
        const int sc  = __builtin_ctzll(bal >> 32);

        // inverse mod 23 from packed scalar table (no LDS on the chain)
        const unsigned long long tt = (sc < 12) ? INV_T0 : INV_T1;
        const int sh  = 5 * (sc - ((sc >= 12) ? 12 : 0));
        const int inv = (int)((tt >> sh) & 31);

        int m = tok - loc;
        m += (m >> 31) & V;            // (tok - loc) mod 23
        const int k = (m * inv) % V;   // compiler magic-mul for %23

        h_pre += (double)sW1[k * HH + tid];   // stride-1, conflict-free
        if (tid == 0) sK[t] = k;
    }

    __syncthreads();
    float* outb = out + (size_t)b * LL * V;
    for (int t = tid; t < LL; t += 256)
        outb[t * V + sK[t]] = 1.0f;
}

extern "C" void kernel_launch(void* const* d_in, const int* in_sizes, int n_in,
                              void* d_out, int out_size, void* d_ws, size_t ws_size,
                              hipStream_t stream) {
    const int*   xtok = (const int*)d_in[0];
    const float* W1   = (const float*)d_in[1];
    const float* b1   = (const float*)d_in[2];
    const float* W2   = (const float*)d_in[3];
    const float* b2   = (const float*)d_in[4];
    float* out = (float*)d_out;

    // d_out poisoned 0xAA pre-launch: zero it, kernel scatters the 1.0s
    hipMemsetAsync(out, 0, (size_t)out_size * sizeof(float), stream);
    daf_kernel<<<BB, 256, 0, stream>>>(xtok, W1, b1, W2, b2, out);
}